// Round 1
// baseline (987.208 us; speedup 1.0000x reference)
//
#include <hip/hip_runtime.h>
#include <hip/hip_bf16.h>
#include <math.h>

// ---------------------------------------------------------------------------
// 2-layer GAT (PyG GATConv, concat=False, add_self_loops=True) on MI355X.
// Strategy: device-side CSR-by-dst build (hist -> scan -> scatter), then per
// layer: fused GEMM+alpha kernel, then per-node softmax-aggregate kernel
// (1 node per 64-lane wave, registers only, no float atomics).
// ---------------------------------------------------------------------------

__device__ __forceinline__ float lrelu(float x) { return x > 0.f ? x : 0.2f * x; }

// ---------------- CSR build ----------------

__global__ void hist_kernel(const int* __restrict__ dst, int* __restrict__ cnt, int E) {
    for (int i = blockIdx.x * blockDim.x + threadIdx.x; i < E; i += gridDim.x * blockDim.x)
        atomicAdd(&cnt[dst[i]], 1);
}

// Single-block exclusive scan over cnt[0..n) -> rowptr[0..n]; also turns cnt
// into a scatter cursor (cnt[i] = rowptr[i]).
__global__ __launch_bounds__(1024) void scan_kernel(int* __restrict__ cnt,
                                                    int* __restrict__ rowptr, int n) {
    __shared__ int sums[1024];
    const int tid = threadIdx.x;
    const int CH = (n + 1023) >> 10;
    const int beg = tid * CH;
    const int end = min(beg + CH, n);
    int s = 0;
    for (int i = beg; i < end; ++i) s += cnt[i];
    sums[tid] = s;
    __syncthreads();
    for (int off = 1; off < 1024; off <<= 1) {
        int v = (tid >= off) ? sums[tid - off] : 0;
        __syncthreads();
        sums[tid] += v;
        __syncthreads();
    }
    int run = sums[tid] - s;  // exclusive prefix
    for (int i = beg; i < end; ++i) {
        int c = cnt[i];
        rowptr[i] = run;
        cnt[i] = run;   // cursor for scatter
        run += c;
    }
    if (tid == 1023) rowptr[n] = sums[1023];
}

__global__ void scatter_kernel(const int* __restrict__ src, const int* __restrict__ dst,
                               int* __restrict__ cursor, int* __restrict__ srcidx, int E) {
    for (int i = blockIdx.x * blockDim.x + threadIdx.x; i < E; i += gridDim.x * blockDim.x) {
        int d = dst[i];
        int pos = atomicAdd(&cursor[d], 1);
        srcidx[pos] = src[i];
    }
}

// ---------------- GEMM + alpha ----------------
// X [n,K] @ W [K,128] -> H8 [n,128] (=[n,4 heads,32]), plus per-node
// alpha_src[n,4], alpha_dst[n,4] (dot of each head's 32 feats with att vecs).
// Block: 256 threads, 32 rows per block (8 rows * 4 batches held in acc regs).
template <int K>
__global__ __launch_bounds__(256) void gemm_alpha(
    const float* __restrict__ X, const float* __restrict__ W,
    const float* __restrict__ AttS, const float* __restrict__ AttD,
    float* __restrict__ H8, float* __restrict__ asrc, float* __restrict__ adst, int n) {
    constexpr int KC = (K < 64) ? K : 64;
    __shared__ __align__(16) float Ws[KC * 128];
    __shared__ __align__(16) float Xs[32 * K];
    const int tid = threadIdx.x;
    const int r = tid >> 5;          // row-in-batch 0..7
    const int sub = tid & 31;
    const int c0 = sub * 4;          // output col base (0..124)
    const int head = sub >> 3;       // 0..3
    const int fc = (sub & 7) * 4;    // feat-in-head base
    const int rowBase = blockIdx.x * 32;

    // stage 32 X rows
    {
        const float4* X4 = (const float4*)X;
        float4* Xs4 = (float4*)Xs;
        const int K4 = K / 4;
        for (int i = tid; i < 32 * K4; i += 256) {
            int rr = rowBase + i / K4;
            Xs4[i] = (rr < n) ? X4[(size_t)rr * K4 + (i % K4)] : make_float4(0.f, 0.f, 0.f, 0.f);
        }
    }

    float acc[4][4] = {};
    for (int kt = 0; kt < K; kt += KC) {
        __syncthreads();
        {
            const float4* W4 = (const float4*)(W + kt * 128);
            float4* Ws4 = (float4*)Ws;
            for (int i = tid; i < KC * 32; i += 256) Ws4[i] = W4[i];
        }
        __syncthreads();
        for (int k = 0; k < KC; ++k) {
            const float4 wv = *(const float4*)&Ws[k * 128 + c0];
#pragma unroll
            for (int b = 0; b < 4; ++b) {
                float xv = Xs[(b * 8 + r) * K + kt + k];
                acc[b][0] = fmaf(xv, wv.x, acc[b][0]);
                acc[b][1] = fmaf(xv, wv.y, acc[b][1]);
                acc[b][2] = fmaf(xv, wv.z, acc[b][2]);
                acc[b][3] = fmaf(xv, wv.w, acc[b][3]);
            }
        }
    }

    float a_s[4], a_d[4];
#pragma unroll
    for (int j = 0; j < 4; ++j) {
        a_s[j] = AttS[head * 32 + fc + j];
        a_d[j] = AttD[head * 32 + fc + j];
    }
#pragma unroll
    for (int b = 0; b < 4; ++b) {
        const int row = rowBase + b * 8 + r;
        if (row < n) {
            *(float4*)&H8[(size_t)row * 128 + c0] =
                make_float4(acc[b][0], acc[b][1], acc[b][2], acc[b][3]);
            float ps = acc[b][0] * a_s[0] + acc[b][1] * a_s[1] +
                       acc[b][2] * a_s[2] + acc[b][3] * a_s[3];
            float pd = acc[b][0] * a_d[0] + acc[b][1] * a_d[1] +
                       acc[b][2] * a_d[2] + acc[b][3] * a_d[3];
#pragma unroll
            for (int msk = 1; msk < 8; msk <<= 1) {
                ps += __shfl_xor(ps, msk);
                pd += __shfl_xor(pd, msk);
            }
            if ((sub & 7) == 0) {
                asrc[row * 4 + head] = ps;
                adst[row * 4 + head] = pd;
            }
        }
    }
}

// ---------------- per-node softmax aggregate ----------------
// One node per 64-lane group. lane = (head-pair 0/1) * 32 + feat; each lane
// owns feat f for heads hp and hp+2. Two passes over in-edges (max, then
// exp/accumulate). Self-loop included inline. Epilogue: head mean + bias
// (+ optional ELU).
__global__ __launch_bounds__(256) void node_kernel(
    const int* __restrict__ rowptr, const int* __restrict__ srcidx,
    const float* __restrict__ H8, const float* __restrict__ asrc,
    const float* __restrict__ adst, const float* __restrict__ bias,
    float* __restrict__ outp, int n, int apply_elu) {
    const int node = blockIdx.x * 4 + (threadIdx.x >> 6);
    if (node >= n) return;
    const int lane = threadIdx.x & 63;
    const int f = lane & 31;
    const int hp = lane >> 5;   // 0/1
    const int h0 = hp, h1 = hp + 2;

    const int beg = rowptr[node], end = rowptr[node + 1];
    const float ad0 = adst[node * 4 + h0], ad1 = adst[node * 4 + h1];
    const float as0 = asrc[node * 4 + h0], as1 = asrc[node * 4 + h1];
    const float e0 = lrelu(as0 + ad0), e1 = lrelu(as1 + ad1);
    float m0 = e0, m1 = e1;
    for (int i = beg; i < end; ++i) {
        const int s = srcidx[i];
        m0 = fmaxf(m0, lrelu(asrc[s * 4 + h0] + ad0));
        m1 = fmaxf(m1, lrelu(asrc[s * 4 + h1] + ad1));
    }
    float p0 = __expf(e0 - m0), p1 = __expf(e1 - m1);
    float s0 = p0, s1 = p1;
    float acc0 = p0 * H8[(size_t)node * 128 + h0 * 32 + f];
    float acc1 = p1 * H8[(size_t)node * 128 + h1 * 32 + f];
    for (int i = beg; i < end; ++i) {
        const int s = srcidx[i];
        const float t0 = lrelu(asrc[s * 4 + h0] + ad0);
        const float t1 = lrelu(asrc[s * 4 + h1] + ad1);
        const float q0 = __expf(t0 - m0), q1 = __expf(t1 - m1);
        s0 += q0; s1 += q1;
        acc0 = fmaf(q0, H8[(size_t)s * 128 + h0 * 32 + f], acc0);
        acc1 = fmaf(q1, H8[(size_t)s * 128 + h1 * 32 + f], acc1);
    }
    float v = acc0 / (s0 + 1e-16f) + acc1 / (s1 + 1e-16f);
    v += __shfl_xor(v, 32);     // add the other head pair
    v = v * 0.25f + bias[f];
    if (apply_elu) v = (v > 0.f) ? v : (__expf(v) - 1.f);
    if (lane < 32) outp[(size_t)node * 32 + f] = v;
}

// ---------------- launch ----------------

extern "C" void kernel_launch(void* const* d_in, const int* in_sizes, int n_in,
                              void* d_out, int out_size, void* d_ws, size_t ws_size,
                              hipStream_t stream) {
    const int N = in_sizes[0] / 128;
    const int E = in_sizes[1] / 2;
    const float* x = (const float*)d_in[0];
    const int* ei = (const int*)d_in[1];
    const float* W1 = (const float*)d_in[2];
    const float* atS1 = (const float*)d_in[3];
    const float* atD1 = (const float*)d_in[4];
    const float* b1 = (const float*)d_in[5];
    const float* W2 = (const float*)d_in[6];
    const float* atS2 = (const float*)d_in[7];
    const float* atD2 = (const float*)d_in[8];
    const float* b2 = (const float*)d_in[9];
    float* out = (float*)d_out;

    char* ws = (char*)d_ws;
    size_t off = 0;
    auto alloc = [&](size_t bytes) {
        void* p = ws + off;
        off = (off + bytes + 255) & ~(size_t)255;
        return p;
    };
    int* cnt = (int*)alloc((size_t)N * 4);          // degree counts -> scatter cursor
    int* rowptr = (int*)alloc((size_t)(N + 1) * 4);
    int* srcidx = (int*)alloc((size_t)E * 4);
    float* h = (float*)alloc((size_t)N * 128 * 4);  // [N,4,32]
    float* av_s = (float*)alloc((size_t)N * 4 * 4);
    float* av_d = (float*)alloc((size_t)N * 4 * 4);
    float* x2 = (float*)alloc((size_t)N * 32 * 4);  // layer-1 output (post-ELU)

    const int* e_src = ei;
    const int* e_dst = ei + E;

    // CSR by destination
    hipMemsetAsync(cnt, 0, (size_t)N * 4, stream);
    hist_kernel<<<1024, 256, 0, stream>>>(e_dst, cnt, E);
    scan_kernel<<<1, 1024, 0, stream>>>(cnt, rowptr, N);
    scatter_kernel<<<1024, 256, 0, stream>>>(e_src, e_dst, cnt, srcidx, E);

    const int gemmGrid = (N + 31) / 32;
    const int nodeGrid = (N + 3) / 4;

    // layer 1
    gemm_alpha<128><<<gemmGrid, 256, 0, stream>>>(x, W1, atS1, atD1, h, av_s, av_d, N);
    node_kernel<<<nodeGrid, 256, 0, stream>>>(rowptr, srcidx, h, av_s, av_d, b1, x2, N, 1);
    // layer 2
    gemm_alpha<32><<<gemmGrid, 256, 0, stream>>>(x2, W2, atS2, atD2, h, av_s, av_d, N);
    node_kernel<<<nodeGrid, 256, 0, stream>>>(rowptr, srcidx, h, av_s, av_d, b2, out, N, 0);
}

// Round 2
// 690.696 us; speedup vs baseline: 1.4293x; 1.4293x over previous
//
#include <hip/hip_runtime.h>
#include <hip/hip_bf16.h>
#include <math.h>

// ---------------------------------------------------------------------------
// 2-layer GAT (PyG GATConv, concat=False, add_self_loops=True) on MI355X.
// R2: single-pass softmax aggregation using a global per-head upper bound on
// asrc (softmax shift-invariance) + unroll-4 gather pipelining in node_kernel.
// ---------------------------------------------------------------------------

__device__ __forceinline__ float lrelu(float x) { return x > 0.f ? x : 0.2f * x; }

// Monotone float<->uint encoding for atomicMax over signed floats.
__device__ __forceinline__ unsigned int fenc(float f) {
    unsigned int u = __float_as_uint(f);
    return (u & 0x80000000u) ? ~u : (u | 0x80000000u);
}
__device__ __forceinline__ float fdec(unsigned int e) {
    unsigned int u = (e & 0x80000000u) ? (e & 0x7FFFFFFFu) : ~e;
    return __uint_as_float(u);
}

// ---------------- CSR build ----------------

__global__ void hist_kernel(const int* __restrict__ dst, int* __restrict__ cnt, int E) {
    for (int i = blockIdx.x * blockDim.x + threadIdx.x; i < E; i += gridDim.x * blockDim.x)
        atomicAdd(&cnt[dst[i]], 1);
}

__global__ __launch_bounds__(1024) void scan_kernel(int* __restrict__ cnt,
                                                    int* __restrict__ rowptr, int n) {
    __shared__ int sums[1024];
    const int tid = threadIdx.x;
    const int CH = (n + 1023) >> 10;
    const int beg = tid * CH;
    const int end = min(beg + CH, n);
    int s = 0;
    for (int i = beg; i < end; ++i) s += cnt[i];
    sums[tid] = s;
    __syncthreads();
    for (int off = 1; off < 1024; off <<= 1) {
        int v = (tid >= off) ? sums[tid - off] : 0;
        __syncthreads();
        sums[tid] += v;
        __syncthreads();
    }
    int run = sums[tid] - s;  // exclusive prefix
    for (int i = beg; i < end; ++i) {
        int c = cnt[i];
        rowptr[i] = run;
        cnt[i] = run;   // cursor for scatter
        run += c;
    }
    if (tid == 1023) rowptr[n] = sums[1023];
}

__global__ void scatter_kernel(const int* __restrict__ src, const int* __restrict__ dst,
                               int* __restrict__ cursor, int* __restrict__ srcidx, int E) {
    for (int i = blockIdx.x * blockDim.x + threadIdx.x; i < E; i += gridDim.x * blockDim.x) {
        int d = dst[i];
        int pos = atomicAdd(&cursor[d], 1);
        srcidx[pos] = src[i];
    }
}

// ---------------- GEMM + alpha ----------------
template <int K>
__global__ __launch_bounds__(256) void gemm_alpha(
    const float* __restrict__ X, const float* __restrict__ W,
    const float* __restrict__ AttS, const float* __restrict__ AttD,
    float* __restrict__ H8, float* __restrict__ asrc, float* __restrict__ adst, int n) {
    constexpr int KC = (K < 64) ? K : 64;
    __shared__ __align__(16) float Ws[KC * 128];
    __shared__ __align__(16) float Xs[32 * K];
    const int tid = threadIdx.x;
    const int r = tid >> 5;          // row-in-batch 0..7
    const int sub = tid & 31;
    const int c0 = sub * 4;          // output col base (0..124)
    const int head = sub >> 3;       // 0..3
    const int fc = (sub & 7) * 4;    // feat-in-head base
    const int rowBase = blockIdx.x * 32;

    {
        const float4* X4 = (const float4*)X;
        float4* Xs4 = (float4*)Xs;
        const int K4 = K / 4;
        for (int i = tid; i < 32 * K4; i += 256) {
            int rr = rowBase + i / K4;
            Xs4[i] = (rr < n) ? X4[(size_t)rr * K4 + (i % K4)] : make_float4(0.f, 0.f, 0.f, 0.f);
        }
    }

    float acc[4][4] = {};
    for (int kt = 0; kt < K; kt += KC) {
        __syncthreads();
        {
            const float4* W4 = (const float4*)(W + kt * 128);
            float4* Ws4 = (float4*)Ws;
            for (int i = tid; i < KC * 32; i += 256) Ws4[i] = W4[i];
        }
        __syncthreads();
        for (int k = 0; k < KC; ++k) {
            const float4 wv = *(const float4*)&Ws[k * 128 + c0];
#pragma unroll
            for (int b = 0; b < 4; ++b) {
                float xv = Xs[(b * 8 + r) * K + kt + k];
                acc[b][0] = fmaf(xv, wv.x, acc[b][0]);
                acc[b][1] = fmaf(xv, wv.y, acc[b][1]);
                acc[b][2] = fmaf(xv, wv.z, acc[b][2]);
                acc[b][3] = fmaf(xv, wv.w, acc[b][3]);
            }
        }
    }

    float a_s[4], a_d[4];
#pragma unroll
    for (int j = 0; j < 4; ++j) {
        a_s[j] = AttS[head * 32 + fc + j];
        a_d[j] = AttD[head * 32 + fc + j];
    }
#pragma unroll
    for (int b = 0; b < 4; ++b) {
        const int row = rowBase + b * 8 + r;
        if (row < n) {
            *(float4*)&H8[(size_t)row * 128 + c0] =
                make_float4(acc[b][0], acc[b][1], acc[b][2], acc[b][3]);
            float ps = acc[b][0] * a_s[0] + acc[b][1] * a_s[1] +
                       acc[b][2] * a_s[2] + acc[b][3] * a_s[3];
            float pd = acc[b][0] * a_d[0] + acc[b][1] * a_d[1] +
                       acc[b][2] * a_d[2] + acc[b][3] * a_d[3];
#pragma unroll
            for (int msk = 1; msk < 8; msk <<= 1) {
                ps += __shfl_xor(ps, msk);
                pd += __shfl_xor(pd, msk);
            }
            if ((sub & 7) == 0) {
                asrc[row * 4 + head] = ps;
                adst[row * 4 + head] = pd;
            }
        }
    }
}

// ---------------- global per-head max of asrc ----------------
__global__ __launch_bounds__(256) void amax_kernel(const float* __restrict__ asrc,
                                                   unsigned int* __restrict__ gmax, int n) {
    float m[4] = {-3.0e38f, -3.0e38f, -3.0e38f, -3.0e38f};
    for (int i = blockIdx.x * blockDim.x + threadIdx.x; i < n; i += gridDim.x * blockDim.x) {
        const float4 v = *(const float4*)&asrc[i * 4];
        m[0] = fmaxf(m[0], v.x); m[1] = fmaxf(m[1], v.y);
        m[2] = fmaxf(m[2], v.z); m[3] = fmaxf(m[3], v.w);
    }
#pragma unroll
    for (int h = 0; h < 4; ++h)
#pragma unroll
        for (int msk = 1; msk < 64; msk <<= 1) m[h] = fmaxf(m[h], __shfl_xor(m[h], msk));
    if ((threadIdx.x & 63) == 0)
#pragma unroll
        for (int h = 0; h < 4; ++h) atomicMax(&gmax[h], fenc(m[h]));
}

// ---------------- per-node single-pass softmax aggregate ----------------
// One node per 64-lane group. lane = (head-pair 0/1)*32 + feat; lane owns
// feat f for heads hp and hp+2. Softmax subtraction constant is the global
// upper bound lrelu(gmax[h]+ad) (shift-invariant, overflow-safe), enabling a
// single pass with unroll-4 gather pipelining.
__global__ __launch_bounds__(256) void node_kernel(
    const int* __restrict__ rowptr, const int* __restrict__ srcidx,
    const float* __restrict__ H8, const float* __restrict__ asrc,
    const float* __restrict__ adst, const unsigned int* __restrict__ gmax,
    const float* __restrict__ bias,
    float* __restrict__ outp, int n, int apply_elu) {
    const int node = blockIdx.x * 4 + (threadIdx.x >> 6);
    if (node >= n) return;
    const int lane = threadIdx.x & 63;
    const int f = lane & 31;
    const int hp = lane >> 5;   // 0/1
    const int h0 = hp, h1 = hp + 2;

    const int beg = rowptr[node], end = rowptr[node + 1];
    const float ad0 = adst[node * 4 + h0], ad1 = adst[node * 4 + h1];
    const float M0 = lrelu(fdec(gmax[h0]) + ad0);
    const float M1 = lrelu(fdec(gmax[h1]) + ad1);

    // self loop
    const float as0 = asrc[node * 4 + h0], as1 = asrc[node * 4 + h1];
    float p0 = __expf(lrelu(as0 + ad0) - M0);
    float p1 = __expf(lrelu(as1 + ad1) - M1);
    float s0 = p0, s1 = p1;
    float acc0 = p0 * H8[(size_t)node * 128 + h0 * 32 + f];
    float acc1 = p1 * H8[(size_t)node * 128 + h1 * 32 + f];

    int i = beg;
    for (; i + 4 <= end; i += 4) {
        const int sa = srcidx[i], sb = srcidx[i + 1], sc = srcidx[i + 2], sd = srcidx[i + 3];
        // issue all gathers up front (independent -> deep MLP)
        const float aa0 = asrc[sa * 4 + h0], aa1 = asrc[sa * 4 + h1];
        const float ab0 = asrc[sb * 4 + h0], ab1 = asrc[sb * 4 + h1];
        const float ac0 = asrc[sc * 4 + h0], ac1 = asrc[sc * 4 + h1];
        const float ad_0 = asrc[sd * 4 + h0], ad_1 = asrc[sd * 4 + h1];
        const float ha0 = H8[(size_t)sa * 128 + h0 * 32 + f], ha1 = H8[(size_t)sa * 128 + h1 * 32 + f];
        const float hb0 = H8[(size_t)sb * 128 + h0 * 32 + f], hb1 = H8[(size_t)sb * 128 + h1 * 32 + f];
        const float hc0 = H8[(size_t)sc * 128 + h0 * 32 + f], hc1 = H8[(size_t)sc * 128 + h1 * 32 + f];
        const float hd0 = H8[(size_t)sd * 128 + h0 * 32 + f], hd1 = H8[(size_t)sd * 128 + h1 * 32 + f];

        const float qa0 = __expf(lrelu(aa0 + ad0) - M0), qa1 = __expf(lrelu(aa1 + ad1) - M1);
        const float qb0 = __expf(lrelu(ab0 + ad0) - M0), qb1 = __expf(lrelu(ab1 + ad1) - M1);
        const float qc0 = __expf(lrelu(ac0 + ad0) - M0), qc1 = __expf(lrelu(ac1 + ad1) - M1);
        const float qd0 = __expf(lrelu(ad_0 + ad0) - M0), qd1 = __expf(lrelu(ad_1 + ad1) - M1);

        s0 += qa0 + qb0 + qc0 + qd0;
        s1 += qa1 + qb1 + qc1 + qd1;
        acc0 = fmaf(qa0, ha0, acc0); acc1 = fmaf(qa1, ha1, acc1);
        acc0 = fmaf(qb0, hb0, acc0); acc1 = fmaf(qb1, hb1, acc1);
        acc0 = fmaf(qc0, hc0, acc0); acc1 = fmaf(qc1, hc1, acc1);
        acc0 = fmaf(qd0, hd0, acc0); acc1 = fmaf(qd1, hd1, acc1);
    }
    for (; i < end; ++i) {
        const int s = srcidx[i];
        const float t0 = lrelu(asrc[s * 4 + h0] + ad0);
        const float t1 = lrelu(asrc[s * 4 + h1] + ad1);
        const float q0 = __expf(t0 - M0), q1 = __expf(t1 - M1);
        s0 += q0; s1 += q1;
        acc0 = fmaf(q0, H8[(size_t)s * 128 + h0 * 32 + f], acc0);
        acc1 = fmaf(q1, H8[(size_t)s * 128 + h1 * 32 + f], acc1);
    }

    float v = acc0 / s0 + acc1 / s1;
    v += __shfl_xor(v, 32);     // add the other head pair
    v = v * 0.25f + bias[f];
    if (apply_elu) v = (v > 0.f) ? v : (__expf(v) - 1.f);
    if (lane < 32) outp[(size_t)node * 32 + f] = v;
}

// ---------------- launch ----------------

extern "C" void kernel_launch(void* const* d_in, const int* in_sizes, int n_in,
                              void* d_out, int out_size, void* d_ws, size_t ws_size,
                              hipStream_t stream) {
    const int N = in_sizes[0] / 128;
    const int E = in_sizes[1] / 2;
    const float* x = (const float*)d_in[0];
    const int* ei = (const int*)d_in[1];
    const float* W1 = (const float*)d_in[2];
    const float* atS1 = (const float*)d_in[3];
    const float* atD1 = (const float*)d_in[4];
    const float* b1 = (const float*)d_in[5];
    const float* W2 = (const float*)d_in[6];
    const float* atS2 = (const float*)d_in[7];
    const float* atD2 = (const float*)d_in[8];
    const float* b2 = (const float*)d_in[9];
    float* out = (float*)d_out;

    char* ws = (char*)d_ws;
    size_t off = 0;
    auto alloc = [&](size_t bytes) {
        void* p = ws + off;
        off = (off + bytes + 255) & ~(size_t)255;
        return p;
    };
    int* cnt = (int*)alloc((size_t)N * 4);
    int* rowptr = (int*)alloc((size_t)(N + 1) * 4);
    int* srcidx = (int*)alloc((size_t)E * 4);
    float* h = (float*)alloc((size_t)N * 128 * 4);
    float* av_s = (float*)alloc((size_t)N * 4 * 4);
    float* av_d = (float*)alloc((size_t)N * 4 * 4);
    float* x2 = (float*)alloc((size_t)N * 32 * 4);
    unsigned int* gmax = (unsigned int*)alloc(4 * sizeof(unsigned int));

    const int* e_src = ei;
    const int* e_dst = ei + E;

    // CSR by destination
    hipMemsetAsync(cnt, 0, (size_t)N * 4, stream);
    hist_kernel<<<1024, 256, 0, stream>>>(e_dst, cnt, E);
    scan_kernel<<<1, 1024, 0, stream>>>(cnt, rowptr, N);
    scatter_kernel<<<1024, 256, 0, stream>>>(e_src, e_dst, cnt, srcidx, E);

    const int gemmGrid = (N + 31) / 32;
    const int nodeGrid = (N + 3) / 4;

    // layer 1
    gemm_alpha<128><<<gemmGrid, 256, 0, stream>>>(x, W1, atS1, atD1, h, av_s, av_d, N);
    hipMemsetAsync(gmax, 0, 4 * sizeof(unsigned int), stream);
    amax_kernel<<<256, 256, 0, stream>>>(av_s, gmax, N);
    node_kernel<<<nodeGrid, 256, 0, stream>>>(rowptr, srcidx, h, av_s, av_d, gmax, b1, x2, N, 1);
    // layer 2
    gemm_alpha<32><<<gemmGrid, 256, 0, stream>>>(x2, W2, atS2, atD2, h, av_s, av_d, N);
    hipMemsetAsync(gmax, 0, 4 * sizeof(unsigned int), stream);
    amax_kernel<<<256, 256, 0, stream>>>(av_s, gmax, N);
    node_kernel<<<nodeGrid, 256, 0, stream>>>(rowptr, srcidx, h, av_s, av_d, gmax, b2, out, N, 0);
}

// Round 3
// 550.734 us; speedup vs baseline: 1.7925x; 1.2541x over previous
//
#include <hip/hip_runtime.h>
#include <hip/hip_bf16.h>
#include <math.h>

// ---------------------------------------------------------------------------
// 2-layer GAT (PyG GATConv, concat=False, add_self_loops=True) on MI355X.
// R3: XCD-affine bucketed scatter (kills 16x write amplification), hist fused
// into layer-1 GEMM dispatch, global-head-max folded into GEMM epilogue,
// unroll-8 gather pipelining in node_kernel.
// ---------------------------------------------------------------------------

__device__ __forceinline__ float lrelu(float x) { return x > 0.f ? x : 0.2f * x; }

// Monotone float<->uint encoding for atomicMax over signed floats.
// fenc(-FLT_MAX) = 0x00800000 > 0, so memset-0 acts as -inf sentinel.
__device__ __forceinline__ unsigned int fenc(float f) {
    unsigned int u = __float_as_uint(f);
    return (u & 0x80000000u) ? ~u : (u | 0x80000000u);
}
__device__ __forceinline__ float fdec(unsigned int e) {
    unsigned int u = (e & 0x80000000u) ? (e & 0x7FFFFFFFu) : ~e;
    return __uint_as_float(u);
}

// ---------------- scan (CSR rowptr) ----------------
__global__ __launch_bounds__(1024) void scan_kernel(int* __restrict__ cnt,
                                                    int* __restrict__ rowptr, int n) {
    __shared__ int sums[1024];
    const int tid = threadIdx.x;
    const int CH = (n + 1023) >> 10;
    const int beg = tid * CH;
    const int end = min(beg + CH, n);
    int s = 0;
    for (int i = beg; i < end; ++i) s += cnt[i];
    sums[tid] = s;
    __syncthreads();
    for (int off = 1; off < 1024; off <<= 1) {
        int v = (tid >= off) ? sums[tid - off] : 0;
        __syncthreads();
        sums[tid] += v;
        __syncthreads();
    }
    int run = sums[tid] - s;  // exclusive prefix
    for (int i = beg; i < end; ++i) {
        int c = cnt[i];
        rowptr[i] = run;
        cnt[i] = run;   // cursor for scatter
        run += c;
    }
    if (tid == 1023) rowptr[n] = sums[1023];
}

// ---------------- bucketed scatter ----------------
// Bucket b (node range [b*npb,(b+1)*npb)) is handled only by blocks with
// blockIdx%8==b, which under round-robin dispatch live on XCD b. srcidx slice
// + cursor slice for a bucket then stay in ONE XCD's L2 -> single writeback.
__global__ __launch_bounds__(256) void scatter_kernel(
    const int* __restrict__ src, const int* __restrict__ dst,
    int* __restrict__ cursor, int* __restrict__ srcidx, int E, int npb) {
    const int b = blockIdx.x & 7;
    const int gb = blockIdx.x >> 3;
    const int nbl = gridDim.x >> 3;
    const int lo = b * npb, hi = lo + npb;
    for (int i = gb * blockDim.x + threadIdx.x; i < E; i += nbl * blockDim.x) {
        const int d = dst[i];
        if (d >= lo && d < hi) {
            int pos = atomicAdd(&cursor[d], 1);
            srcidx[pos] = src[i];
        }
    }
}

// ---------------- GEMM + alpha (+ fused hist + global head max) ----------------
// Blocks [0, gemmGrid): X[n,K] @ W[K,128] -> H8[n,128], alpha_src/dst[n,4],
//   block-reduced atomicMax into gmax[4].
// Blocks [gemmGrid, gemmGrid+histGrid): histogram of dst into cnt.
template <int K>
__global__ __launch_bounds__(256) void gemm_hist(
    const float* __restrict__ X, const float* __restrict__ W,
    const float* __restrict__ AttS, const float* __restrict__ AttD,
    float* __restrict__ H8, float* __restrict__ asrc, float* __restrict__ adst,
    unsigned int* __restrict__ gmax, int n, int gemmGrid,
    const int* __restrict__ dst, int* __restrict__ cnt, int E) {
    constexpr int KC = (K < 64) ? K : 64;
    __shared__ __align__(16) float Ws[KC * 128];
    __shared__ __align__(16) float Xs[32 * K];
    __shared__ unsigned int smax[4];
    const int tid = threadIdx.x;

    if (blockIdx.x >= gemmGrid) {
        // ---- hist role ----
        const int hb = blockIdx.x - gemmGrid;
        const int histBlocks = gridDim.x - gemmGrid;
        for (int i = hb * blockDim.x + tid; i < E; i += histBlocks * blockDim.x)
            atomicAdd(&cnt[dst[i]], 1);
        return;
    }

    // ---- gemm role ----
    const int r = tid >> 5;          // row-in-batch 0..7
    const int sub = tid & 31;
    const int c0 = sub * 4;          // output col base (0..124)
    const int head = sub >> 3;       // 0..3
    const int fc = (sub & 7) * 4;    // feat-in-head base
    const int rowBase = blockIdx.x * 32;

    if (tid < 4) smax[tid] = 0u;
    {
        const float4* X4 = (const float4*)X;
        float4* Xs4 = (float4*)Xs;
        const int K4 = K / 4;
        for (int i = tid; i < 32 * K4; i += 256) {
            int rr = rowBase + i / K4;
            Xs4[i] = (rr < n) ? X4[(size_t)rr * K4 + (i % K4)] : make_float4(0.f, 0.f, 0.f, 0.f);
        }
    }

    float acc[4][4] = {};
    for (int kt = 0; kt < K; kt += KC) {
        __syncthreads();
        {
            const float4* W4 = (const float4*)(W + kt * 128);
            float4* Ws4 = (float4*)Ws;
            for (int i = tid; i < KC * 32; i += 256) Ws4[i] = W4[i];
        }
        __syncthreads();
        for (int k = 0; k < KC; ++k) {
            const float4 wv = *(const float4*)&Ws[k * 128 + c0];
#pragma unroll
            for (int b = 0; b < 4; ++b) {
                float xv = Xs[(b * 8 + r) * K + kt + k];
                acc[b][0] = fmaf(xv, wv.x, acc[b][0]);
                acc[b][1] = fmaf(xv, wv.y, acc[b][1]);
                acc[b][2] = fmaf(xv, wv.z, acc[b][2]);
                acc[b][3] = fmaf(xv, wv.w, acc[b][3]);
            }
        }
    }

    float a_s[4], a_d[4];
#pragma unroll
    for (int j = 0; j < 4; ++j) {
        a_s[j] = AttS[head * 32 + fc + j];
        a_d[j] = AttD[head * 32 + fc + j];
    }
#pragma unroll
    for (int b = 0; b < 4; ++b) {
        const int row = rowBase + b * 8 + r;
        if (row < n) {
            *(float4*)&H8[(size_t)row * 128 + c0] =
                make_float4(acc[b][0], acc[b][1], acc[b][2], acc[b][3]);
            float ps = acc[b][0] * a_s[0] + acc[b][1] * a_s[1] +
                       acc[b][2] * a_s[2] + acc[b][3] * a_s[3];
            float pd = acc[b][0] * a_d[0] + acc[b][1] * a_d[1] +
                       acc[b][2] * a_d[2] + acc[b][3] * a_d[3];
#pragma unroll
            for (int msk = 1; msk < 8; msk <<= 1) {
                ps += __shfl_xor(ps, msk);
                pd += __shfl_xor(pd, msk);
            }
            if ((sub & 7) == 0) {
                asrc[row * 4 + head] = ps;
                adst[row * 4 + head] = pd;
                atomicMax(&smax[head], fenc(ps));
            }
        }
    }
    __syncthreads();
    if (tid < 4) atomicMax(&gmax[tid], smax[tid]);
}

// ---------------- per-node single-pass softmax aggregate ----------------
// One node per 64-lane group. lane = (head-pair 0/1)*32 + feat; lane owns
// feat f for heads hp and hp+2. Softmax constant = global upper bound
// lrelu(gmax[h]+ad) (shift-invariant), single pass, unroll-8 gathers.
__global__ __launch_bounds__(256) void node_kernel(
    const int* __restrict__ rowptr, const int* __restrict__ srcidx,
    const float* __restrict__ H8, const float* __restrict__ asrc,
    const float* __restrict__ adst, const unsigned int* __restrict__ gmax,
    const float* __restrict__ bias,
    float* __restrict__ outp, int n, int apply_elu) {
    const int node = blockIdx.x * 4 + (threadIdx.x >> 6);
    if (node >= n) return;
    const int lane = threadIdx.x & 63;
    const int f = lane & 31;
    const int hp = lane >> 5;   // 0/1
    const int h0 = hp, h1 = hp + 2;

    const int beg = rowptr[node], end = rowptr[node + 1];
    const float ad0 = adst[node * 4 + h0], ad1 = adst[node * 4 + h1];
    const float M0 = lrelu(fdec(gmax[h0]) + ad0);
    const float M1 = lrelu(fdec(gmax[h1]) + ad1);

    // self loop
    const float as0 = asrc[node * 4 + h0], as1 = asrc[node * 4 + h1];
    float p0 = __expf(lrelu(as0 + ad0) - M0);
    float p1 = __expf(lrelu(as1 + ad1) - M1);
    float s0 = p0, s1 = p1;
    float acc0 = p0 * H8[(size_t)node * 128 + h0 * 32 + f];
    float acc1 = p1 * H8[(size_t)node * 128 + h1 * 32 + f];

    int i = beg;
    for (; i + 8 <= end; i += 8) {
        int sv[8];
#pragma unroll
        for (int u = 0; u < 8; ++u) sv[u] = srcidx[i + u];
        float a0[8], a1[8], hv0[8], hv1[8];
#pragma unroll
        for (int u = 0; u < 8; ++u) {
            a0[u] = asrc[sv[u] * 4 + h0];
            a1[u] = asrc[sv[u] * 4 + h1];
        }
#pragma unroll
        for (int u = 0; u < 8; ++u) {
            hv0[u] = H8[(size_t)sv[u] * 128 + h0 * 32 + f];
            hv1[u] = H8[(size_t)sv[u] * 128 + h1 * 32 + f];
        }
#pragma unroll
        for (int u = 0; u < 8; ++u) {
            const float q0 = __expf(lrelu(a0[u] + ad0) - M0);
            const float q1 = __expf(lrelu(a1[u] + ad1) - M1);
            s0 += q0; s1 += q1;
            acc0 = fmaf(q0, hv0[u], acc0);
            acc1 = fmaf(q1, hv1[u], acc1);
        }
    }
    for (; i < end; ++i) {
        const int s = srcidx[i];
        const float t0 = lrelu(asrc[s * 4 + h0] + ad0);
        const float t1 = lrelu(asrc[s * 4 + h1] + ad1);
        const float q0 = __expf(t0 - M0), q1 = __expf(t1 - M1);
        s0 += q0; s1 += q1;
        acc0 = fmaf(q0, H8[(size_t)s * 128 + h0 * 32 + f], acc0);
        acc1 = fmaf(q1, H8[(size_t)s * 128 + h1 * 32 + f], acc1);
    }

    float v = acc0 / s0 + acc1 / s1;
    v += __shfl_xor(v, 32);     // add the other head pair
    v = v * 0.25f + bias[f];
    if (apply_elu) v = (v > 0.f) ? v : (__expf(v) - 1.f);
    if (lane < 32) outp[(size_t)node * 32 + f] = v;
}

// ---------------- launch ----------------

extern "C" void kernel_launch(void* const* d_in, const int* in_sizes, int n_in,
                              void* d_out, int out_size, void* d_ws, size_t ws_size,
                              hipStream_t stream) {
    const int N = in_sizes[0] / 128;
    const int E = in_sizes[1] / 2;
    const float* x = (const float*)d_in[0];
    const int* ei = (const int*)d_in[1];
    const float* W1 = (const float*)d_in[2];
    const float* atS1 = (const float*)d_in[3];
    const float* atD1 = (const float*)d_in[4];
    const float* b1 = (const float*)d_in[5];
    const float* W2 = (const float*)d_in[6];
    const float* atS2 = (const float*)d_in[7];
    const float* atD2 = (const float*)d_in[8];
    const float* b2 = (const float*)d_in[9];
    float* out = (float*)d_out;

    char* ws = (char*)d_ws;
    size_t off = 0;
    auto alloc = [&](size_t bytes) {
        void* p = ws + off;
        off = (off + bytes + 255) & ~(size_t)255;
        return p;
    };
    int* cnt = (int*)alloc((size_t)N * 4);
    unsigned int* gmax = (unsigned int*)alloc(8 * sizeof(unsigned int)); // [layer][head]
    const size_t zeroBytes = off;  // cnt + gmax zeroed in one memset
    int* rowptr = (int*)alloc((size_t)(N + 1) * 4);
    int* srcidx = (int*)alloc((size_t)E * 4);
    float* h = (float*)alloc((size_t)N * 128 * 4);
    float* av_s = (float*)alloc((size_t)N * 4 * 4);
    float* av_d = (float*)alloc((size_t)N * 4 * 4);
    float* x2 = (float*)alloc((size_t)N * 32 * 4);

    const int* e_src = ei;
    const int* e_dst = ei + E;

    const int gemmGrid = (N + 31) / 32;
    const int histGrid = 1024;
    const int nodeGrid = (N + 3) / 4;
    const int npb = (N + 7) / 8;

    hipMemsetAsync(cnt, 0, zeroBytes, stream);

    // layer-1 GEMM + hist (independent, fused dispatch)
    gemm_hist<128><<<gemmGrid + histGrid, 256, 0, stream>>>(
        x, W1, atS1, atD1, h, av_s, av_d, gmax, N, gemmGrid, e_dst, cnt, E);
    scan_kernel<<<1, 1024, 0, stream>>>(cnt, rowptr, N);
    scatter_kernel<<<2048, 256, 0, stream>>>(e_src, e_dst, cnt, srcidx, E, npb);
    node_kernel<<<nodeGrid, 256, 0, stream>>>(rowptr, srcidx, h, av_s, av_d, gmax, b1, x2, N, 1);
    // layer 2
    gemm_hist<32><<<gemmGrid, 256, 0, stream>>>(
        x2, W2, atS2, atD2, h, av_s, av_d, gmax + 4, N, gemmGrid, e_dst, cnt, E);
    node_kernel<<<nodeGrid, 256, 0, stream>>>(rowptr, srcidx, h, av_s, av_d, gmax + 4, b2, out, N, 0);
}

// Round 4
// 545.439 us; speedup vs baseline: 1.8099x; 1.0097x over previous
//
#include <hip/hip_runtime.h>
#include <hip/hip_bf16.h>
#include <math.h>

// ---------------------------------------------------------------------------
// 2-layer GAT (PyG GATConv, concat=False, add_self_loops=True) on MI355X.
// R4: node_kernel address-slimming — srcidx pre-scaled to byte offsets,
// head-interleaved [0,2,1,3] layouts for H8/asrc/adst/gmax so each lane's two
// heads are adjacent (dwordx2 + imm-offset loads), float2-paired math.
// ---------------------------------------------------------------------------

__device__ __forceinline__ float lrelu(float x) { return x > 0.f ? x : 0.2f * x; }

// Monotone float<->uint encoding for atomicMax over signed floats.
// fenc(-FLT_MAX) > 0, so memset-0 acts as a -inf sentinel.
__device__ __forceinline__ unsigned int fenc(float f) {
    unsigned int u = __float_as_uint(f);
    return (u & 0x80000000u) ? ~u : (u | 0x80000000u);
}
__device__ __forceinline__ float fdec(unsigned int e) {
    unsigned int u = (e & 0x80000000u) ? (e & 0x7FFFFFFFu) : ~e;
    return __uint_as_float(u);
}

// ---------------- scan (CSR rowptr) ----------------
__global__ __launch_bounds__(1024) void scan_kernel(int* __restrict__ cnt,
                                                    int* __restrict__ rowptr, int n) {
    __shared__ int sums[1024];
    const int tid = threadIdx.x;
    const int CH = (n + 1023) >> 10;
    const int beg = tid * CH;
    const int end = min(beg + CH, n);
    int s = 0;
    for (int i = beg; i < end; ++i) s += cnt[i];
    sums[tid] = s;
    __syncthreads();
    for (int off = 1; off < 1024; off <<= 1) {
        int v = (tid >= off) ? sums[tid - off] : 0;
        __syncthreads();
        sums[tid] += v;
        __syncthreads();
    }
    int run = sums[tid] - s;  // exclusive prefix
    for (int i = beg; i < end; ++i) {
        int c = cnt[i];
        rowptr[i] = run;
        cnt[i] = run;   // cursor for scatter
        run += c;
    }
    if (tid == 1023) rowptr[n] = sums[1023];
}

// ---------------- bucketed scatter ----------------
// Bucket b (node range [b*npb,(b+1)*npb)) handled only by blocks with
// blockIdx%8==b (round-robin XCD dispatch) -> srcidx/cursor slices stay in
// one XCD's L2. Stores src*16 (byte offset into asrc) for fast node gathers.
__global__ __launch_bounds__(256) void scatter_kernel(
    const int* __restrict__ src, const int* __restrict__ dst,
    int* __restrict__ cursor, int* __restrict__ srcidx, int E, int npb) {
    const int b = blockIdx.x & 7;
    const int gb = blockIdx.x >> 3;
    const int nbl = gridDim.x >> 3;
    const int lo = b * npb, hi = lo + npb;
    for (int i = gb * blockDim.x + threadIdx.x; i < E; i += nbl * blockDim.x) {
        const int d = dst[i];
        if (d >= lo && d < hi) {
            int pos = atomicAdd(&cursor[d], 1);
            srcidx[pos] = src[i] << 4;
        }
    }
}

// ---------------- GEMM + alpha (+ fused hist + global head max) ----------------
// Head-interleaved output layouts: head h goes to position pos(h) = [0,2,1,3]
// so that heads (hp, hp+2) are adjacent blocks for the node kernel.
template <int K>
__global__ __launch_bounds__(256) void gemm_hist(
    const float* __restrict__ X, const float* __restrict__ W,
    const float* __restrict__ AttS, const float* __restrict__ AttD,
    float* __restrict__ H8, float* __restrict__ asrc, float* __restrict__ adst,
    unsigned int* __restrict__ gmax, int n, int gemmGrid,
    const int* __restrict__ dst, int* __restrict__ cnt, int E) {
    constexpr int KC = (K < 64) ? K : 64;
    __shared__ __align__(16) float Ws[KC * 128];
    __shared__ __align__(16) float Xs[32 * K];
    __shared__ unsigned int smax[4];
    const int tid = threadIdx.x;

    if (blockIdx.x >= gemmGrid) {
        // ---- hist role ----
        const int hb = blockIdx.x - gemmGrid;
        const int histBlocks = gridDim.x - gemmGrid;
        for (int i = hb * blockDim.x + tid; i < E; i += histBlocks * blockDim.x)
            atomicAdd(&cnt[dst[i]], 1);
        return;
    }

    // ---- gemm role ----
    const int r = tid >> 5;          // row-in-batch 0..7
    const int sub = tid & 31;
    const int c0 = sub * 4;          // input col base (0..124)
    const int head = sub >> 3;       // 0..3
    const int pos = ((head & 1) << 1) | (head >> 1);  // [0,2,1,3] order
    const int fc = (sub & 7) * 4;    // feat-in-head base
    const int rowBase = blockIdx.x * 32;

    if (tid < 4) smax[tid] = 0u;
    {
        const float4* X4 = (const float4*)X;
        float4* Xs4 = (float4*)Xs;
        const int K4 = K / 4;
        for (int i = tid; i < 32 * K4; i += 256) {
            int rr = rowBase + i / K4;
            Xs4[i] = (rr < n) ? X4[(size_t)rr * K4 + (i % K4)] : make_float4(0.f, 0.f, 0.f, 0.f);
        }
    }

    float acc[4][4] = {};
    for (int kt = 0; kt < K; kt += KC) {
        __syncthreads();
        {
            const float4* W4 = (const float4*)(W + kt * 128);
            float4* Ws4 = (float4*)Ws;
            for (int i = tid; i < KC * 32; i += 256) Ws4[i] = W4[i];
        }
        __syncthreads();
        for (int k = 0; k < KC; ++k) {
            const float4 wv = *(const float4*)&Ws[k * 128 + c0];
#pragma unroll
            for (int b = 0; b < 4; ++b) {
                float xv = Xs[(b * 8 + r) * K + kt + k];
                acc[b][0] = fmaf(xv, wv.x, acc[b][0]);
                acc[b][1] = fmaf(xv, wv.y, acc[b][1]);
                acc[b][2] = fmaf(xv, wv.z, acc[b][2]);
                acc[b][3] = fmaf(xv, wv.w, acc[b][3]);
            }
        }
    }

    float a_s[4], a_d[4];
#pragma unroll
    for (int j = 0; j < 4; ++j) {
        a_s[j] = AttS[head * 32 + fc + j];
        a_d[j] = AttD[head * 32 + fc + j];
    }
#pragma unroll
    for (int b = 0; b < 4; ++b) {
        const int row = rowBase + b * 8 + r;
        if (row < n) {
            // head-interleaved column position
            *(float4*)&H8[(size_t)row * 128 + pos * 32 + fc] =
                make_float4(acc[b][0], acc[b][1], acc[b][2], acc[b][3]);
            float ps = acc[b][0] * a_s[0] + acc[b][1] * a_s[1] +
                       acc[b][2] * a_s[2] + acc[b][3] * a_s[3];
            float pd = acc[b][0] * a_d[0] + acc[b][1] * a_d[1] +
                       acc[b][2] * a_d[2] + acc[b][3] * a_d[3];
#pragma unroll
            for (int msk = 1; msk < 8; msk <<= 1) {
                ps += __shfl_xor(ps, msk);
                pd += __shfl_xor(pd, msk);
            }
            if ((sub & 7) == 0) {
                asrc[row * 4 + pos] = ps;
                adst[row * 4 + pos] = pd;
                atomicMax(&smax[pos], fenc(ps));
            }
        }
    }
    __syncthreads();
    if (tid < 4) atomicMax(&gmax[tid], smax[tid]);
}

// ---------------- per-node single-pass softmax aggregate ----------------
// One node per 64-lane group; lane = hp*32 + f owns heads (hp, hp+2) which
// are ADJACENT in the interleaved layouts. All gathers are 32-bit voffsets
// off SGPR bases; the two H8 loads share one address (+128 imm offset).
__global__ __launch_bounds__(256) void node_kernel(
    const int* __restrict__ rowptr, const int* __restrict__ srcidx,
    const float* __restrict__ H8, const float* __restrict__ asrc,
    const float* __restrict__ adst, const unsigned int* __restrict__ gmax,
    const float* __restrict__ bias,
    float* __restrict__ outp, int n, int apply_elu) {
    const int node = blockIdx.x * 4 + (threadIdx.x >> 6);
    if (node >= n) return;
    const int lane = threadIdx.x & 63;
    const unsigned f = lane & 31;
    const unsigned hp = lane >> 5;            // 0/1
    const unsigned hp8 = hp * 8;              // byte off into asrc/adst row
    const unsigned hpf4 = hp * 256 + f * 4;   // byte off into H8 row
    const unsigned node16 = (unsigned)node * 16;
    const char* aB = (const char*)asrc;
    const char* dB = (const char*)adst;
    const char* hB = (const char*)H8;

    const int beg = rowptr[node], end = rowptr[node + 1];
    const float2 ad01 = *(const float2*)(dB + node16 + hp8);
    const float2 M01 = make_float2(lrelu(fdec(gmax[hp * 2]) + ad01.x),
                                   lrelu(fdec(gmax[hp * 2 + 1]) + ad01.y));

    // self loop
    const float2 aself = *(const float2*)(aB + node16 + hp8);
    float2 q = make_float2(__expf(lrelu(aself.x + ad01.x) - M01.x),
                           __expf(lrelu(aself.y + ad01.y) - M01.y));
    float2 s01 = q;
    const unsigned hoffSelf = ((unsigned)node << 9) + hpf4;
    float2 acc01 = make_float2(q.x * *(const float*)(hB + hoffSelf),
                               q.y * *(const float*)(hB + hoffSelf + 128));

    int i = beg;
    for (; i + 8 <= end; i += 8) {
        unsigned sx[8];
#pragma unroll
        for (int u = 0; u < 8; ++u) sx[u] = (unsigned)srcidx[i + u];  // s*16
        float2 a[8];
#pragma unroll
        for (int u = 0; u < 8; ++u) a[u] = *(const float2*)(aB + sx[u] + hp8);
        float hv0[8], hv1[8];
#pragma unroll
        for (int u = 0; u < 8; ++u) {
            const unsigned hoff = (sx[u] << 5) + hpf4;
            hv0[u] = *(const float*)(hB + hoff);
            hv1[u] = *(const float*)(hB + hoff + 128);
        }
#pragma unroll
        for (int u = 0; u < 8; ++u) {
            const float tx = a[u].x + ad01.x, ty = a[u].y + ad01.y;
            const float lx = fmaxf(tx, 0.2f * tx), ly = fmaxf(ty, 0.2f * ty);
            const float qx = __expf(lx - M01.x), qy = __expf(ly - M01.y);
            s01.x += qx; s01.y += qy;
            acc01.x = fmaf(qx, hv0[u], acc01.x);
            acc01.y = fmaf(qy, hv1[u], acc01.y);
        }
    }
    for (; i < end; ++i) {
        const unsigned sx = (unsigned)srcidx[i];
        const float2 a = *(const float2*)(aB + sx + hp8);
        const unsigned hoff = (sx << 5) + hpf4;
        const float tx = a.x + ad01.x, ty = a.y + ad01.y;
        const float lx = fmaxf(tx, 0.2f * tx), ly = fmaxf(ty, 0.2f * ty);
        const float qx = __expf(lx - M01.x), qy = __expf(ly - M01.y);
        s01.x += qx; s01.y += qy;
        acc01.x = fmaf(qx, *(const float*)(hB + hoff), acc01.x);
        acc01.y = fmaf(qy, *(const float*)(hB + hoff + 128), acc01.y);
    }

    float v = acc01.x / s01.x + acc01.y / s01.y;
    v += __shfl_xor(v, 32);     // add the other head pair
    v = v * 0.25f + bias[f];
    if (apply_elu) v = (v > 0.f) ? v : (__expf(v) - 1.f);
    if (lane < 32) outp[(size_t)node * 32 + f] = v;
}

// ---------------- launch ----------------

extern "C" void kernel_launch(void* const* d_in, const int* in_sizes, int n_in,
                              void* d_out, int out_size, void* d_ws, size_t ws_size,
                              hipStream_t stream) {
    const int N = in_sizes[0] / 128;
    const int E = in_sizes[1] / 2;
    const float* x = (const float*)d_in[0];
    const int* ei = (const int*)d_in[1];
    const float* W1 = (const float*)d_in[2];
    const float* atS1 = (const float*)d_in[3];
    const float* atD1 = (const float*)d_in[4];
    const float* b1 = (const float*)d_in[5];
    const float* W2 = (const float*)d_in[6];
    const float* atS2 = (const float*)d_in[7];
    const float* atD2 = (const float*)d_in[8];
    const float* b2 = (const float*)d_in[9];
    float* out = (float*)d_out;

    char* ws = (char*)d_ws;
    size_t off = 0;
    auto alloc = [&](size_t bytes) {
        void* p = ws + off;
        off = (off + bytes + 255) & ~(size_t)255;
        return p;
    };
    int* cnt = (int*)alloc((size_t)N * 4);
    unsigned int* gmax = (unsigned int*)alloc(8 * sizeof(unsigned int)); // [layer][pos]
    const size_t zeroBytes = off;  // cnt + gmax zeroed in one memset
    int* rowptr = (int*)alloc((size_t)(N + 1) * 4);
    int* srcidx = (int*)alloc((size_t)E * 4);
    float* h = (float*)alloc((size_t)N * 128 * 4);
    float* av_s = (float*)alloc((size_t)N * 4 * 4);
    float* av_d = (float*)alloc((size_t)N * 4 * 4);
    float* x2 = (float*)alloc((size_t)N * 32 * 4);

    const int* e_src = ei;
    const int* e_dst = ei + E;

    const int gemmGrid = (N + 31) / 32;
    const int histGrid = 1024;
    const int nodeGrid = (N + 3) / 4;
    const int npb = (N + 7) / 8;

    hipMemsetAsync(cnt, 0, zeroBytes, stream);

    // layer-1 GEMM + hist (independent, fused dispatch)
    gemm_hist<128><<<gemmGrid + histGrid, 256, 0, stream>>>(
        x, W1, atS1, atD1, h, av_s, av_d, gmax, N, gemmGrid, e_dst, cnt, E);
    scan_kernel<<<1, 1024, 0, stream>>>(cnt, rowptr, N);
    scatter_kernel<<<2048, 256, 0, stream>>>(e_src, e_dst, cnt, srcidx, E, npb);
    node_kernel<<<nodeGrid, 256, 0, stream>>>(rowptr, srcidx, h, av_s, av_d, gmax, b1, x2, N, 1);
    // layer 2
    gemm_hist<32><<<gemmGrid, 256, 0, stream>>>(
        x2, W2, atS2, atD2, h, av_s, av_d, gmax + 4, N, gemmGrid, e_dst, cnt, E);
    node_kernel<<<nodeGrid, 256, 0, stream>>>(rowptr, srcidx, h, av_s, av_d, gmax + 4, b2, out, N, 0);
}

// Round 5
// 511.650 us; speedup vs baseline: 1.9295x; 1.0660x over previous
//
#include <hip/hip_runtime.h>
#include <hip/hip_bf16.h>
#include <math.h>

// ---------------------------------------------------------------------------
// 2-layer GAT (PyG GATConv, concat=False, add_self_loops=True) on MI355X.
// R5: h stored as packed bf16 (head-pair interleaved: one dword = both heads
// for a lane) -> gather bytes/edge halved (512->256B) and Hb (12.8MB) mostly
// L2-resident. Non-temporal srcidx stream. Alphas/exp stay fp32.
// ---------------------------------------------------------------------------

__device__ __forceinline__ float lrelu(float x) { return x > 0.f ? x : 0.2f * x; }

// Monotone float<->uint encoding for atomicMax over signed floats.
// fenc(-FLT_MAX) > 0, so memset-0 acts as a -inf sentinel.
__device__ __forceinline__ unsigned int fenc(float f) {
    unsigned int u = __float_as_uint(f);
    return (u & 0x80000000u) ? ~u : (u | 0x80000000u);
}
__device__ __forceinline__ float fdec(unsigned int e) {
    unsigned int u = (e & 0x80000000u) ? (e & 0x7FFFFFFFu) : ~e;
    return __uint_as_float(u);
}

// bf16 round-to-nearest-even pack/unpack
__device__ __forceinline__ unsigned short f2bf(float x) {
    unsigned u = __float_as_uint(x);
    return (unsigned short)((u + 0x7FFFu + ((u >> 16) & 1u)) >> 16);
}
__device__ __forceinline__ float bflo(unsigned w) { return __uint_as_float(w << 16); }
__device__ __forceinline__ float bfhi(unsigned w) { return __uint_as_float(w & 0xFFFF0000u); }

// ---------------- scan (CSR rowptr) ----------------
__global__ __launch_bounds__(1024) void scan_kernel(int* __restrict__ cnt,
                                                    int* __restrict__ rowptr, int n) {
    __shared__ int sums[1024];
    const int tid = threadIdx.x;
    const int CH = (n + 1023) >> 10;
    const int beg = tid * CH;
    const int end = min(beg + CH, n);
    int s = 0;
    for (int i = beg; i < end; ++i) s += cnt[i];
    sums[tid] = s;
    __syncthreads();
    for (int off = 1; off < 1024; off <<= 1) {
        int v = (tid >= off) ? sums[tid - off] : 0;
        __syncthreads();
        sums[tid] += v;
        __syncthreads();
    }
    int run = sums[tid] - s;  // exclusive prefix
    for (int i = beg; i < end; ++i) {
        int c = cnt[i];
        rowptr[i] = run;
        cnt[i] = run;   // cursor for scatter
        run += c;
    }
    if (tid == 1023) rowptr[n] = sums[1023];
}

// ---------------- bucketed scatter ----------------
// Bucket b (node range [b*npb,(b+1)*npb)) handled only by blocks with
// blockIdx%8==b (round-robin XCD dispatch) -> srcidx/cursor slices stay in
// one XCD's L2. Stores src*16 (byte offset into asrc) for fast node gathers.
__global__ __launch_bounds__(256) void scatter_kernel(
    const int* __restrict__ src, const int* __restrict__ dst,
    int* __restrict__ cursor, int* __restrict__ srcidx, int E, int npb) {
    const int b = blockIdx.x & 7;
    const int gb = blockIdx.x >> 3;
    const int nbl = gridDim.x >> 3;
    const int lo = b * npb, hi = lo + npb;
    for (int i = gb * blockDim.x + threadIdx.x; i < E; i += nbl * blockDim.x) {
        const int d = dst[i];
        if (d >= lo && d < hi) {
            int pos = atomicAdd(&cursor[d], 1);
            __builtin_nontemporal_store(src[i] << 4, &srcidx[pos]);
        }
    }
}

// ---------------- GEMM + alpha (+ fused hist + global head max) ----------------
// Hb layout (bf16): byte off = row*256 + (head&1)*128 + f*4 + (head>>1)*2
//   -> for lane (hp,f): one dword holds heads (hp, hp+2).
// asrc/adst layout: [row*4 + pos], pos(head) = [0,2,1,3] interleave.
template <int K>
__global__ __launch_bounds__(256) void gemm_hist(
    const float* __restrict__ X, const float* __restrict__ W,
    const float* __restrict__ AttS, const float* __restrict__ AttD,
    unsigned short* __restrict__ Hb, float* __restrict__ asrc, float* __restrict__ adst,
    unsigned int* __restrict__ gmax, int n, int gemmGrid,
    const int* __restrict__ dst, int* __restrict__ cnt, int E) {
    constexpr int KC = (K < 64) ? K : 64;
    __shared__ __align__(16) float Ws[KC * 128];
    __shared__ __align__(16) float Xs[32 * K];
    __shared__ unsigned int smax[4];
    const int tid = threadIdx.x;

    if (blockIdx.x >= gemmGrid) {
        // ---- hist role ----
        const int hb = blockIdx.x - gemmGrid;
        const int histBlocks = gridDim.x - gemmGrid;
        for (int i = hb * blockDim.x + tid; i < E; i += histBlocks * blockDim.x)
            atomicAdd(&cnt[dst[i]], 1);
        return;
    }

    // ---- gemm role ----
    const int r = tid >> 5;          // row-in-batch 0..7
    const int sub = tid & 31;
    const int c0 = sub * 4;          // output col base (0..124)
    const int head = sub >> 3;       // 0..3
    const int pos = ((head & 1) << 1) | (head >> 1);  // [0,2,1,3] order
    const int fc = (sub & 7) * 4;    // feat-in-head base
    const int rowBase = blockIdx.x * 32;

    if (tid < 4) smax[tid] = 0u;
    {
        const float4* X4 = (const float4*)X;
        float4* Xs4 = (float4*)Xs;
        const int K4 = K / 4;
        for (int i = tid; i < 32 * K4; i += 256) {
            int rr = rowBase + i / K4;
            Xs4[i] = (rr < n) ? X4[(size_t)rr * K4 + (i % K4)] : make_float4(0.f, 0.f, 0.f, 0.f);
        }
    }

    float acc[4][4] = {};
    for (int kt = 0; kt < K; kt += KC) {
        __syncthreads();
        {
            const float4* W4 = (const float4*)(W + kt * 128);
            float4* Ws4 = (float4*)Ws;
            for (int i = tid; i < KC * 32; i += 256) Ws4[i] = W4[i];
        }
        __syncthreads();
        for (int k = 0; k < KC; ++k) {
            const float4 wv = *(const float4*)&Ws[k * 128 + c0];
#pragma unroll
            for (int b = 0; b < 4; ++b) {
                float xv = Xs[(b * 8 + r) * K + kt + k];
                acc[b][0] = fmaf(xv, wv.x, acc[b][0]);
                acc[b][1] = fmaf(xv, wv.y, acc[b][1]);
                acc[b][2] = fmaf(xv, wv.z, acc[b][2]);
                acc[b][3] = fmaf(xv, wv.w, acc[b][3]);
            }
        }
    }

    float a_s[4], a_d[4];
#pragma unroll
    for (int j = 0; j < 4; ++j) {
        a_s[j] = AttS[head * 32 + fc + j];
        a_d[j] = AttD[head * 32 + fc + j];
    }
    // u16 index pieces: row*128 + (head&1)*64 + f*2 + (head>>1)
    const unsigned hbase_head = (unsigned)(head & 1) * 64 + (unsigned)(head >> 1) + fc * 2;
#pragma unroll
    for (int b = 0; b < 4; ++b) {
        const int row = rowBase + b * 8 + r;
        if (row < n) {
            const unsigned hbase = (unsigned)row * 128 + hbase_head;
            Hb[hbase + 0] = f2bf(acc[b][0]);
            Hb[hbase + 2] = f2bf(acc[b][1]);
            Hb[hbase + 4] = f2bf(acc[b][2]);
            Hb[hbase + 6] = f2bf(acc[b][3]);
            float ps = acc[b][0] * a_s[0] + acc[b][1] * a_s[1] +
                       acc[b][2] * a_s[2] + acc[b][3] * a_s[3];
            float pd = acc[b][0] * a_d[0] + acc[b][1] * a_d[1] +
                       acc[b][2] * a_d[2] + acc[b][3] * a_d[3];
#pragma unroll
            for (int msk = 1; msk < 8; msk <<= 1) {
                ps += __shfl_xor(ps, msk);
                pd += __shfl_xor(pd, msk);
            }
            if ((sub & 7) == 0) {
                asrc[row * 4 + pos] = ps;
                adst[row * 4 + pos] = pd;
                atomicMax(&smax[pos], fenc(ps));
            }
        }
    }
    __syncthreads();
    if (tid < 4) atomicMax(&gmax[tid], smax[tid]);
}

// ---------------- per-node single-pass softmax aggregate ----------------
// One node per 64-lane group; lane = hp*32 + f owns heads (hp, hp+2), which
// share ONE dword in Hb. All gathers are 32-bit voffsets off SGPR bases.
__global__ __launch_bounds__(256) void node_kernel(
    const int* __restrict__ rowptr, const int* __restrict__ srcidx,
    const unsigned short* __restrict__ Hb, const float* __restrict__ asrc,
    const float* __restrict__ adst, const unsigned int* __restrict__ gmax,
    const float* __restrict__ bias,
    float* __restrict__ outp, int n, int apply_elu) {
    const int node = blockIdx.x * 4 + (threadIdx.x >> 6);
    if (node >= n) return;
    const int lane = threadIdx.x & 63;
    const unsigned f = lane & 31;
    const unsigned hp = lane >> 5;            // 0/1
    const unsigned hp8 = hp * 8;              // byte off into asrc/adst row (16B)
    const unsigned hpf = hp * 128 + f * 4;    // byte off into Hb row (256B)
    const unsigned node16 = (unsigned)node * 16;
    const char* aB = (const char*)asrc;
    const char* dB = (const char*)adst;
    const char* hB = (const char*)Hb;

    const int beg = rowptr[node], end = rowptr[node + 1];
    const float2 ad01 = *(const float2*)(dB + node16 + hp8);
    const float2 M01 = make_float2(lrelu(fdec(gmax[hp * 2]) + ad01.x),
                                   lrelu(fdec(gmax[hp * 2 + 1]) + ad01.y));

    // self loop
    const float2 aself = *(const float2*)(aB + node16 + hp8);
    float2 q = make_float2(__expf(lrelu(aself.x + ad01.x) - M01.x),
                           __expf(lrelu(aself.y + ad01.y) - M01.y));
    float2 s01 = q;
    const unsigned wSelf = *(const unsigned*)(hB + (node16 << 4) + hpf);
    float2 acc01 = make_float2(q.x * bflo(wSelf), q.y * bfhi(wSelf));

    int i = beg;
    for (; i + 8 <= end; i += 8) {
        unsigned sx[8];
#pragma unroll
        for (int u = 0; u < 8; ++u)
            sx[u] = (unsigned)__builtin_nontemporal_load(&srcidx[i + u]);  // s*16
        float2 a[8];
#pragma unroll
        for (int u = 0; u < 8; ++u) a[u] = *(const float2*)(aB + sx[u] + hp8);
        unsigned w[8];
#pragma unroll
        for (int u = 0; u < 8; ++u) w[u] = *(const unsigned*)(hB + (sx[u] << 4) + hpf);
#pragma unroll
        for (int u = 0; u < 8; ++u) {
            const float tx = a[u].x + ad01.x, ty = a[u].y + ad01.y;
            const float lx = fmaxf(tx, 0.2f * tx), ly = fmaxf(ty, 0.2f * ty);
            const float qx = __expf(lx - M01.x), qy = __expf(ly - M01.y);
            s01.x += qx; s01.y += qy;
            acc01.x = fmaf(qx, bflo(w[u]), acc01.x);
            acc01.y = fmaf(qy, bfhi(w[u]), acc01.y);
        }
    }
    for (; i < end; ++i) {
        const unsigned sx = (unsigned)__builtin_nontemporal_load(&srcidx[i]);
        const float2 a = *(const float2*)(aB + sx + hp8);
        const unsigned wv = *(const unsigned*)(hB + (sx << 4) + hpf);
        const float tx = a.x + ad01.x, ty = a.y + ad01.y;
        const float lx = fmaxf(tx, 0.2f * tx), ly = fmaxf(ty, 0.2f * ty);
        const float qx = __expf(lx - M01.x), qy = __expf(ly - M01.y);
        s01.x += qx; s01.y += qy;
        acc01.x = fmaf(qx, bflo(wv), acc01.x);
        acc01.y = fmaf(qy, bfhi(wv), acc01.y);
    }

    float v = acc01.x / s01.x + acc01.y / s01.y;
    v += __shfl_xor(v, 32);     // add the other head pair
    v = v * 0.25f + bias[f];
    if (apply_elu) v = (v > 0.f) ? v : (__expf(v) - 1.f);
    if (lane < 32) outp[(size_t)node * 32 + f] = v;
}

// ---------------- launch ----------------

extern "C" void kernel_launch(void* const* d_in, const int* in_sizes, int n_in,
                              void* d_out, int out_size, void* d_ws, size_t ws_size,
                              hipStream_t stream) {
    const int N = in_sizes[0] / 128;
    const int E = in_sizes[1] / 2;
    const float* x = (const float*)d_in[0];
    const int* ei = (const int*)d_in[1];
    const float* W1 = (const float*)d_in[2];
    const float* atS1 = (const float*)d_in[3];
    const float* atD1 = (const float*)d_in[4];
    const float* b1 = (const float*)d_in[5];
    const float* W2 = (const float*)d_in[6];
    const float* atS2 = (const float*)d_in[7];
    const float* atD2 = (const float*)d_in[8];
    const float* b2 = (const float*)d_in[9];
    float* out = (float*)d_out;

    char* ws = (char*)d_ws;
    size_t off = 0;
    auto alloc = [&](size_t bytes) {
        void* p = ws + off;
        off = (off + bytes + 255) & ~(size_t)255;
        return p;
    };
    int* cnt = (int*)alloc((size_t)N * 4);
    unsigned int* gmax = (unsigned int*)alloc(8 * sizeof(unsigned int)); // [layer][pos]
    const size_t zeroBytes = off;  // cnt + gmax zeroed in one memset
    int* rowptr = (int*)alloc((size_t)(N + 1) * 4);
    int* srcidx = (int*)alloc((size_t)E * 4);
    unsigned short* hb = (unsigned short*)alloc((size_t)N * 128 * 2);  // packed bf16
    float* av_s = (float*)alloc((size_t)N * 4 * 4);
    float* av_d = (float*)alloc((size_t)N * 4 * 4);
    float* x2 = (float*)alloc((size_t)N * 32 * 4);

    const int* e_src = ei;
    const int* e_dst = ei + E;

    const int gemmGrid = (N + 31) / 32;
    const int histGrid = 1024;
    const int nodeGrid = (N + 3) / 4;
    const int npb = (N + 7) / 8;

    hipMemsetAsync(cnt, 0, zeroBytes, stream);

    // layer-1 GEMM + hist (independent, fused dispatch)
    gemm_hist<128><<<gemmGrid + histGrid, 256, 0, stream>>>(
        x, W1, atS1, atD1, hb, av_s, av_d, gmax, N, gemmGrid, e_dst, cnt, E);
    scan_kernel<<<1, 1024, 0, stream>>>(cnt, rowptr, N);
    scatter_kernel<<<2048, 256, 0, stream>>>(e_src, e_dst, cnt, srcidx, E, npb);
    node_kernel<<<nodeGrid, 256, 0, stream>>>(rowptr, srcidx, hb, av_s, av_d, gmax, b1, x2, N, 1);
    // layer 2
    gemm_hist<32><<<gemmGrid, 256, 0, stream>>>(
        x2, W2, atS2, atD2, hb, av_s, av_d, gmax + 4, N, gemmGrid, e_dst, cnt, E);
    node_kernel<<<nodeGrid, 256, 0, stream>>>(rowptr, srcidx, hb, av_s, av_d, gmax + 4, b2, out, N, 0);
}

// Round 6
// 426.243 us; speedup vs baseline: 2.3161x; 1.2004x over previous
//
#include <hip/hip_runtime.h>
#include <hip/hip_bf16.h>
#include <math.h>

// ---------------------------------------------------------------------------
// 2-layer GAT (PyG GATConv, concat=False, add_self_loops=True) on MI355X.
// R6: hierarchical 3-stage CSR scan (was: 109us single-block scan),
// int4-vectorized bucketed scatter, node_kernel unroll 16/4/1.
// Hb stays packed bf16 head-pair-interleaved (one dword = lane's two heads).
// ---------------------------------------------------------------------------

__device__ __forceinline__ float lrelu(float x) { return x > 0.f ? x : 0.2f * x; }

// Monotone float<->uint encoding for atomicMax over signed floats.
// fenc(-FLT_MAX) > 0, so memset-0 acts as a -inf sentinel.
__device__ __forceinline__ unsigned int fenc(float f) {
    unsigned int u = __float_as_uint(f);
    return (u & 0x80000000u) ? ~u : (u | 0x80000000u);
}
__device__ __forceinline__ float fdec(unsigned int e) {
    unsigned int u = (e & 0x80000000u) ? (e & 0x7FFFFFFFu) : ~e;
    return __uint_as_float(u);
}

// bf16 round-to-nearest-even pack/unpack
__device__ __forceinline__ unsigned short f2bf(float x) {
    unsigned u = __float_as_uint(x);
    return (unsigned short)((u + 0x7FFFu + ((u >> 16) & 1u)) >> 16);
}
__device__ __forceinline__ float bflo(unsigned w) { return __uint_as_float(w << 16); }
__device__ __forceinline__ float bfhi(unsigned w) { return __uint_as_float(w & 0xFFFF0000u); }

// ---------------- hierarchical scan (CSR rowptr + cursor) ----------------
// Requires n <= 256*256 = 65536.
__global__ __launch_bounds__(256) void scan_part(const int* __restrict__ cnt,
                                                 int* __restrict__ bsum, int n) {
    __shared__ int red[256];
    const int t = threadIdx.x;
    const int i = blockIdx.x * 256 + t;
    red[t] = (i < n) ? cnt[i] : 0;
    __syncthreads();
    for (int o = 128; o > 0; o >>= 1) {
        if (t < o) red[t] += red[t + o];
        __syncthreads();
    }
    if (t == 0) bsum[blockIdx.x] = red[0];
}

__global__ __launch_bounds__(256) void scan_mid(const int* __restrict__ bsum,
                                                int* __restrict__ boff, int nb,
                                                int* __restrict__ rowptr, int n) {
    __shared__ int s[256];
    const int t = threadIdx.x;
    const int v = (t < nb) ? bsum[t] : 0;
    s[t] = v;
    __syncthreads();
    for (int o = 1; o < 256; o <<= 1) {
        const int u = (t >= o) ? s[t - o] : 0;
        __syncthreads();
        s[t] += u;
        __syncthreads();
    }
    if (t < nb) boff[t] = s[t] - v;   // exclusive block offset
    if (t == 255) rowptr[n] = s[255]; // total
}

__global__ __launch_bounds__(256) void scan_final(const int* __restrict__ cnt,
                                                  const int* __restrict__ boff,
                                                  int* __restrict__ rowptr,
                                                  int* __restrict__ cursor, int n) {
    __shared__ int s[256];
    const int t = threadIdx.x;
    const int i = blockIdx.x * 256 + t;
    const int v = (i < n) ? cnt[i] : 0;
    s[t] = v;
    __syncthreads();
    for (int o = 1; o < 256; o <<= 1) {
        const int u = (t >= o) ? s[t - o] : 0;
        __syncthreads();
        s[t] += u;
        __syncthreads();
    }
    if (i < n) {
        const int ex = boff[blockIdx.x] + s[t] - v;
        rowptr[i] = ex;
        cursor[i] = ex;
    }
}

// ---------------- bucketed scatter (int4-vectorized) ----------------
// Bucket b (node range [b*npb,(b+1)*npb)) handled only by blocks with
// blockIdx%8==b (round-robin XCD dispatch) -> srcidx/cursor slices stay in
// one XCD's L2. Stores src*16 (byte offset) for fast node gathers.
__global__ __launch_bounds__(256) void scatter_kernel(
    const int* __restrict__ src, const int* __restrict__ dst,
    int* __restrict__ cursor, int* __restrict__ srcidx, int E, int npb) {
    const int b = blockIdx.x & 7;
    const int gb = blockIdx.x >> 3;
    const int nbl = gridDim.x >> 3;
    const int lo = b * npb, hi = lo + npb;
    const int E4 = E >> 2;
    const int4* dst4 = (const int4*)dst;
    const int4* src4 = (const int4*)src;
    for (int i = gb * blockDim.x + threadIdx.x; i < E4; i += nbl * blockDim.x) {
        const int4 d = dst4[i];
        const int4 s = src4[i];
        if (d.x >= lo && d.x < hi)
            __builtin_nontemporal_store(s.x << 4, &srcidx[atomicAdd(&cursor[d.x], 1)]);
        if (d.y >= lo && d.y < hi)
            __builtin_nontemporal_store(s.y << 4, &srcidx[atomicAdd(&cursor[d.y], 1)]);
        if (d.z >= lo && d.z < hi)
            __builtin_nontemporal_store(s.z << 4, &srcidx[atomicAdd(&cursor[d.z], 1)]);
        if (d.w >= lo && d.w < hi)
            __builtin_nontemporal_store(s.w << 4, &srcidx[atomicAdd(&cursor[d.w], 1)]);
    }
    // tail (E not multiple of 4)
    if (blockIdx.x == 0 && threadIdx.x < (E & 3)) {
        const int i = (E4 << 2) + threadIdx.x;
        const int d = dst[i];
        if (d >= lo && d < hi) {
            int pos = atomicAdd(&cursor[d], 1);
            __builtin_nontemporal_store(src[i] << 4, &srcidx[pos]);
        }
    }
}

// ---------------- GEMM + alpha (+ fused hist + global head max) ----------------
// Hb layout (bf16): u16 idx = row*128 + (head&1)*64 + f*2 + (head>>1)
//   -> for lane (hp,f): one dword holds heads (hp, hp+2).
// asrc/adst layout: [row*4 + pos], pos(head) = [0,2,1,3] interleave.
template <int K>
__global__ __launch_bounds__(256) void gemm_hist(
    const float* __restrict__ X, const float* __restrict__ W,
    const float* __restrict__ AttS, const float* __restrict__ AttD,
    unsigned short* __restrict__ Hb, float* __restrict__ asrc, float* __restrict__ adst,
    unsigned int* __restrict__ gmax, int n, int gemmGrid,
    const int* __restrict__ dst, int* __restrict__ cnt, int E) {
    constexpr int KC = (K < 64) ? K : 64;
    __shared__ __align__(16) float Ws[KC * 128];
    __shared__ __align__(16) float Xs[32 * K];
    __shared__ unsigned int smax[4];
    const int tid = threadIdx.x;

    if (blockIdx.x >= gemmGrid) {
        // ---- hist role ----
        const int hb = blockIdx.x - gemmGrid;
        const int histBlocks = gridDim.x - gemmGrid;
        const int E4 = E >> 2;
        const int4* dst4 = (const int4*)dst;
        for (int i = hb * blockDim.x + tid; i < E4; i += histBlocks * blockDim.x) {
            const int4 d = dst4[i];
            atomicAdd(&cnt[d.x], 1);
            atomicAdd(&cnt[d.y], 1);
            atomicAdd(&cnt[d.z], 1);
            atomicAdd(&cnt[d.w], 1);
        }
        if (hb == 0 && tid < (E & 3)) atomicAdd(&cnt[dst[(E4 << 2) + tid]], 1);
        return;
    }

    // ---- gemm role ----
    const int r = tid >> 5;          // row-in-batch 0..7
    const int sub = tid & 31;
    const int c0 = sub * 4;          // output col base (0..124)
    const int head = sub >> 3;       // 0..3
    const int pos = ((head & 1) << 1) | (head >> 1);  // [0,2,1,3] order
    const int fc = (sub & 7) * 4;    // feat-in-head base
    const int rowBase = blockIdx.x * 32;

    if (tid < 4) smax[tid] = 0u;
    {
        const float4* X4 = (const float4*)X;
        float4* Xs4 = (float4*)Xs;
        const int K4 = K / 4;
        for (int i = tid; i < 32 * K4; i += 256) {
            int rr = rowBase + i / K4;
            Xs4[i] = (rr < n) ? X4[(size_t)rr * K4 + (i % K4)] : make_float4(0.f, 0.f, 0.f, 0.f);
        }
    }

    float acc[4][4] = {};
    for (int kt = 0; kt < K; kt += KC) {
        __syncthreads();
        {
            const float4* W4 = (const float4*)(W + kt * 128);
            float4* Ws4 = (float4*)Ws;
            for (int i = tid; i < KC * 32; i += 256) Ws4[i] = W4[i];
        }
        __syncthreads();
        for (int k = 0; k < KC; ++k) {
            const float4 wv = *(const float4*)&Ws[k * 128 + c0];
#pragma unroll
            for (int b = 0; b < 4; ++b) {
                float xv = Xs[(b * 8 + r) * K + kt + k];
                acc[b][0] = fmaf(xv, wv.x, acc[b][0]);
                acc[b][1] = fmaf(xv, wv.y, acc[b][1]);
                acc[b][2] = fmaf(xv, wv.z, acc[b][2]);
                acc[b][3] = fmaf(xv, wv.w, acc[b][3]);
            }
        }
    }

    float a_s[4], a_d[4];
#pragma unroll
    for (int j = 0; j < 4; ++j) {
        a_s[j] = AttS[head * 32 + fc + j];
        a_d[j] = AttD[head * 32 + fc + j];
    }
    // u16 index pieces: row*128 + (head&1)*64 + f*2 + (head>>1)
    const unsigned hbase_head = (unsigned)(head & 1) * 64 + (unsigned)(head >> 1) + fc * 2;
#pragma unroll
    for (int b = 0; b < 4; ++b) {
        const int row = rowBase + b * 8 + r;
        if (row < n) {
            const unsigned hbase = (unsigned)row * 128 + hbase_head;
            Hb[hbase + 0] = f2bf(acc[b][0]);
            Hb[hbase + 2] = f2bf(acc[b][1]);
            Hb[hbase + 4] = f2bf(acc[b][2]);
            Hb[hbase + 6] = f2bf(acc[b][3]);
            float ps = acc[b][0] * a_s[0] + acc[b][1] * a_s[1] +
                       acc[b][2] * a_s[2] + acc[b][3] * a_s[3];
            float pd = acc[b][0] * a_d[0] + acc[b][1] * a_d[1] +
                       acc[b][2] * a_d[2] + acc[b][3] * a_d[3];
#pragma unroll
            for (int msk = 1; msk < 8; msk <<= 1) {
                ps += __shfl_xor(ps, msk);
                pd += __shfl_xor(pd, msk);
            }
            if ((sub & 7) == 0) {
                asrc[row * 4 + pos] = ps;
                adst[row * 4 + pos] = pd;
                atomicMax(&smax[pos], fenc(ps));
            }
        }
    }
    __syncthreads();
    if (tid < 4) atomicMax(&gmax[tid], smax[tid]);
}

// ---------------- per-node single-pass softmax aggregate ----------------
// One node per 64-lane group; lane = hp*32 + f owns heads (hp, hp+2), which
// share ONE dword in Hb. All gathers are 32-bit voffsets off SGPR bases.
// Unroll tiers 16/4/1 for deep miss-level parallelism.
__global__ __launch_bounds__(256) void node_kernel(
    const int* __restrict__ rowptr, const int* __restrict__ srcidx,
    const unsigned short* __restrict__ Hb, const float* __restrict__ asrc,
    const float* __restrict__ adst, const unsigned int* __restrict__ gmax,
    const float* __restrict__ bias,
    float* __restrict__ outp, int n, int apply_elu) {
    const int node = blockIdx.x * 4 + (threadIdx.x >> 6);
    if (node >= n) return;
    const int lane = threadIdx.x & 63;
    const unsigned f = lane & 31;
    const unsigned hp = lane >> 5;            // 0/1
    const unsigned hp8 = hp * 8;              // byte off into asrc/adst row (16B)
    const unsigned hpf = hp * 128 + f * 4;    // byte off into Hb row (256B)
    const unsigned node16 = (unsigned)node * 16;
    const char* aB = (const char*)asrc;
    const char* dB = (const char*)adst;
    const char* hB = (const char*)Hb;

    const int beg = rowptr[node], end = rowptr[node + 1];
    const float2 ad01 = *(const float2*)(dB + node16 + hp8);
    const float2 M01 = make_float2(lrelu(fdec(gmax[hp * 2]) + ad01.x),
                                   lrelu(fdec(gmax[hp * 2 + 1]) + ad01.y));

    // self loop
    const float2 aself = *(const float2*)(aB + node16 + hp8);
    float2 q = make_float2(__expf(lrelu(aself.x + ad01.x) - M01.x),
                           __expf(lrelu(aself.y + ad01.y) - M01.y));
    float2 s01 = q;
    const unsigned wSelf = *(const unsigned*)(hB + (node16 << 4) + hpf);
    float2 acc01 = make_float2(q.x * bflo(wSelf), q.y * bfhi(wSelf));

    int i = beg;
    for (; i + 16 <= end; i += 16) {
        unsigned sx[16];
#pragma unroll
        for (int u = 0; u < 16; ++u)
            sx[u] = (unsigned)__builtin_nontemporal_load(&srcidx[i + u]);  // s*16
        float2 a[16];
#pragma unroll
        for (int u = 0; u < 16; ++u) a[u] = *(const float2*)(aB + sx[u] + hp8);
        unsigned w[16];
#pragma unroll
        for (int u = 0; u < 16; ++u) w[u] = *(const unsigned*)(hB + (sx[u] << 4) + hpf);
#pragma unroll
        for (int u = 0; u < 16; ++u) {
            const float tx = a[u].x + ad01.x, ty = a[u].y + ad01.y;
            const float lx = fmaxf(tx, 0.2f * tx), ly = fmaxf(ty, 0.2f * ty);
            const float qx = __expf(lx - M01.x), qy = __expf(ly - M01.y);
            s01.x += qx; s01.y += qy;
            acc01.x = fmaf(qx, bflo(w[u]), acc01.x);
            acc01.y = fmaf(qy, bfhi(w[u]), acc01.y);
        }
    }
    for (; i + 4 <= end; i += 4) {
        unsigned sx[4];
#pragma unroll
        for (int u = 0; u < 4; ++u)
            sx[u] = (unsigned)__builtin_nontemporal_load(&srcidx[i + u]);
        float2 a[4];
#pragma unroll
        for (int u = 0; u < 4; ++u) a[u] = *(const float2*)(aB + sx[u] + hp8);
        unsigned w[4];
#pragma unroll
        for (int u = 0; u < 4; ++u) w[u] = *(const unsigned*)(hB + (sx[u] << 4) + hpf);
#pragma unroll
        for (int u = 0; u < 4; ++u) {
            const float tx = a[u].x + ad01.x, ty = a[u].y + ad01.y;
            const float lx = fmaxf(tx, 0.2f * tx), ly = fmaxf(ty, 0.2f * ty);
            const float qx = __expf(lx - M01.x), qy = __expf(ly - M01.y);
            s01.x += qx; s01.y += qy;
            acc01.x = fmaf(qx, bflo(w[u]), acc01.x);
            acc01.y = fmaf(qy, bfhi(w[u]), acc01.y);
        }
    }
    for (; i < end; ++i) {
        const unsigned sx = (unsigned)__builtin_nontemporal_load(&srcidx[i]);
        const float2 a = *(const float2*)(aB + sx + hp8);
        const unsigned wv = *(const unsigned*)(hB + (sx << 4) + hpf);
        const float tx = a.x + ad01.x, ty = a.y + ad01.y;
        const float lx = fmaxf(tx, 0.2f * tx), ly = fmaxf(ty, 0.2f * ty);
        const float qx = __expf(lx - M01.x), qy = __expf(ly - M01.y);
        s01.x += qx; s01.y += qy;
        acc01.x = fmaf(qx, bflo(wv), acc01.x);
        acc01.y = fmaf(qy, bfhi(wv), acc01.y);
    }

    float v = acc01.x / s01.x + acc01.y / s01.y;
    v += __shfl_xor(v, 32);     // add the other head pair
    v = v * 0.25f + bias[f];
    if (apply_elu) v = (v > 0.f) ? v : (__expf(v) - 1.f);
    if (lane < 32) outp[(size_t)node * 32 + f] = v;
}

// ---------------- launch ----------------

extern "C" void kernel_launch(void* const* d_in, const int* in_sizes, int n_in,
                              void* d_out, int out_size, void* d_ws, size_t ws_size,
                              hipStream_t stream) {
    const int N = in_sizes[0] / 128;
    const int E = in_sizes[1] / 2;
    const float* x = (const float*)d_in[0];
    const int* ei = (const int*)d_in[1];
    const float* W1 = (const float*)d_in[2];
    const float* atS1 = (const float*)d_in[3];
    const float* atD1 = (const float*)d_in[4];
    const float* b1 = (const float*)d_in[5];
    const float* W2 = (const float*)d_in[6];
    const float* atS2 = (const float*)d_in[7];
    const float* atD2 = (const float*)d_in[8];
    const float* b2 = (const float*)d_in[9];
    float* out = (float*)d_out;

    char* ws = (char*)d_ws;
    size_t off = 0;
    auto alloc = [&](size_t bytes) {
        void* p = ws + off;
        off = (off + bytes + 255) & ~(size_t)255;
        return p;
    };
    int* cnt = (int*)alloc((size_t)N * 4);
    unsigned int* gmax = (unsigned int*)alloc(8 * sizeof(unsigned int)); // [layer][pos]
    const size_t zeroBytes = off;  // cnt + gmax zeroed in one memset
    int* rowptr = (int*)alloc((size_t)(N + 1) * 4);
    int* cursor = (int*)alloc((size_t)N * 4);
    int* bsum = (int*)alloc(256 * 4);
    int* boff = (int*)alloc(256 * 4);
    int* srcidx = (int*)alloc((size_t)E * 4);
    unsigned short* hb = (unsigned short*)alloc((size_t)N * 128 * 2);  // packed bf16
    float* av_s = (float*)alloc((size_t)N * 4 * 4);
    float* av_d = (float*)alloc((size_t)N * 4 * 4);
    float* x2 = (float*)alloc((size_t)N * 32 * 4);

    const int* e_src = ei;
    const int* e_dst = ei + E;

    const int gemmGrid = (N + 31) / 32;
    const int histGrid = 1024;
    const int nodeGrid = (N + 3) / 4;
    const int npb = (N + 7) / 8;
    const int scanGrid = (N + 255) / 256;   // must be <= 256

    hipMemsetAsync(cnt, 0, zeroBytes, stream);

    // layer-1 GEMM + hist (independent, fused dispatch)
    gemm_hist<128><<<gemmGrid + histGrid, 256, 0, stream>>>(
        x, W1, atS1, atD1, hb, av_s, av_d, gmax, N, gemmGrid, e_dst, cnt, E);
    scan_part<<<scanGrid, 256, 0, stream>>>(cnt, bsum, N);
    scan_mid<<<1, 256, 0, stream>>>(bsum, boff, scanGrid, rowptr, N);
    scan_final<<<scanGrid, 256, 0, stream>>>(cnt, boff, rowptr, cursor, N);
    scatter_kernel<<<2048, 256, 0, stream>>>(e_src, e_dst, cursor, srcidx, E, npb);
    node_kernel<<<nodeGrid, 256, 0, stream>>>(rowptr, srcidx, hb, av_s, av_d, gmax, b1, x2, N, 1);
    // layer 2
    gemm_hist<32><<<gemmGrid, 256, 0, stream>>>(
        x2, W2, atS2, atD2, hb, av_s, av_d, gmax + 4, N, gemmGrid, e_dst, cnt, E);
    node_kernel<<<nodeGrid, 256, 0, stream>>>(rowptr, srcidx, hb, av_s, av_d, gmax + 4, b2, out, N, 0);
}